// Round 6
// baseline (95.195 us; speedup 1.0000x reference)
//
#include <hip/hip_runtime.h>

typedef __bf16 bf16x8 __attribute__((ext_vector_type(8)));
typedef float f32x4 __attribute__((ext_vector_type(4)));

#define D_DIM 256
// base-2 scale: sv2 = acc * INV_T * log2(e); exp(sv)=2^(sv2)
#define C2 2.88539008f
#define LN2 0.69314718f

__device__ __forceinline__ unsigned short f2bf(float f) {
  union { float f; unsigned u; } x; x.f = f;
  unsigned r = x.u + 0x7FFFu + ((x.u >> 16) & 1u);  // round-to-nearest-even
  return (unsigned short)(r >> 16);
}

// ---------------- Kernel 1: L2-normalize [emb_i; emb_j] -> bf16 R[N][256] ----
__global__ __launch_bounds__(256) void k_normalize(const float* __restrict__ ei,
                                                   const float* __restrict__ ej,
                                                   unsigned short* __restrict__ R,
                                                   unsigned* __restrict__ ticket,
                                                   int B) {
  if (blockIdx.x == 0 && threadIdx.x == 0) *ticket = 0u;  // per-call reset
  const int w = threadIdx.x >> 6, lane = threadIdx.x & 63;
  const int row = blockIdx.x * 4 + w;
  const float* src = (row < B) ? (ei + (size_t)row * D_DIM)
                               : (ej + (size_t)(row - B) * D_DIM);
  float4 v = reinterpret_cast<const float4*>(src)[lane];  // 64 lanes * 4 = 256
  float ss = v.x * v.x + v.y * v.y + v.z * v.z + v.w * v.w;
#pragma unroll
  for (int d = 32; d; d >>= 1) ss += __shfl_xor(ss, d, 64);
  float s = 1.0f / fmaxf(sqrtf(ss), 1e-12f);
  ushort4 o;
  o.x = f2bf(v.x * s); o.y = f2bf(v.y * s);
  o.z = f2bf(v.z * s); o.w = f2bf(v.w * s);
  reinterpret_cast<ushort4*>(R + (size_t)row * D_DIM)[lane] = o;
}

// ---------------- Kernel 2: symmetric fused sim GEMM + exp partials ---------
// Upper-triangular 128x128 tiles (bi <= bj); off-diag tiles feed both row and
// column blocks (sim symmetric). NO LDS: MFMA fragments load directly from
// global (L2-resident R, 4MB). Each global_load_dwordx4 covers 16 contiguous
// 64B segments (fully coalesced); intra-block panel reuse (2 waves share each
// panel) is L1-resident (4KB/step). No barriers -> 16 independent waves/CU,
// compiler software-pipelines the unrolled K loop.
__global__ __launch_bounds__(256) void k_simgemm(const unsigned short* __restrict__ R,
                                                 float* __restrict__ rowPartial,
                                                 float* __restrict__ simTgt,
                                                 int N) {
  const int tid = threadIdx.x;
  const int w = tid >> 6, lane = tid & 63;
  const int wr = w >> 1, wc = w & 1;
  const int half = N >> 1;

  // decode linear block id -> upper-triangular (bi, bj), bi <= bj
  const int T = N / 128;  // 64
  const int t = blockIdx.x;
  int bi = (int)(((float)(2 * T + 1) -
                  sqrtf((float)((2 * T + 1) * (2 * T + 1) - 8 * t))) * 0.5f);
  while (bi > 0 && t < bi * (2 * T - bi + 1) / 2) --bi;
  while (t >= (bi + 1) * (2 * T - bi) / 2) ++bi;
  const int bj = bi + (t - bi * (2 * T - bi + 1) / 2);
  const int brow = bi * 128, bcol = bj * 128;
  const bool offdiag = (bi != bj);

  f32x4 zero4 = {0.f, 0.f, 0.f, 0.f};
  f32x4 acc[4][4];
#pragma unroll
  for (int m = 0; m < 4; ++m)
#pragma unroll
    for (int n = 0; n < 4; ++n) acc[m][n] = zero4;

  // per-lane fragment base addresses (row = lane&15 within 16-row frag,
  // 16B chunk = lane>>4 within the 64B K-slice)
  const unsigned short* aBase = R + (size_t)(brow + wr * 64 + (lane & 15)) * D_DIM + (lane >> 4) * 8;
  const unsigned short* bBase = R + (size_t)(bcol + wc * 64 + (lane & 15)) * D_DIM + (lane >> 4) * 8;

#pragma unroll
  for (int kt = 0; kt < 8; ++kt) {  // K = 256 = 8 * 32
    bf16x8 a[4], b[4];
#pragma unroll
    for (int m = 0; m < 4; ++m)
      a[m] = *reinterpret_cast<const bf16x8*>(aBase + (size_t)m * 16 * D_DIM + kt * 32);
#pragma unroll
    for (int n = 0; n < 4; ++n)
      b[n] = *reinterpret_cast<const bf16x8*>(bBase + (size_t)n * 16 * D_DIM + kt * 32);
#pragma unroll
    for (int m = 0; m < 4; ++m)
#pragma unroll
      for (int n = 0; n < 4; ++n)
        acc[m][n] = __builtin_amdgcn_mfma_f32_16x16x32_bf16(a[m], b[n], acc[m][n], 0, 0, 0);
  }

  // epilogue (base-2): scale, mask diag, capture targets, exp2, row-direction
  // sums (over tile cols) + column-direction sums (over rows, symmetry)
  float cs[4] = {0.f, 0.f, 0.f, 0.f};
#pragma unroll
  for (int m = 0; m < 4; ++m) {
#pragma unroll
    for (int j = 0; j < 4; ++j) {
      const int gr = brow + wr * 64 + m * 16 + (lane >> 4) * 4 + j;
      const int tgt = (gr < half) ? gr + half : gr - half;
      float rs = 0.f;
#pragma unroll
      for (int n = 0; n < 4; ++n) {
        const int gc = bcol + wc * 64 + n * 16 + (lane & 15);
        const float sv2 = acc[m][n][j] * C2;
        const float ev = (gr == gc) ? 0.f : __builtin_amdgcn_exp2f(sv2);
        if (gc == tgt) {                  // involution: also gr == tgt(gc)
          simTgt[gr] = sv2;
          if (offdiag) simTgt[gc] = sv2;  // sim symmetric
        }
        rs += ev;
        cs[n] += ev;
      }
#pragma unroll
      for (int d = 1; d < 16; d <<= 1) rs += __shfl_xor(rs, d, 64);
      if ((lane & 15) == 0)
        rowPartial[(size_t)(bj * 2 + wc) * N + gr] = rs;
    }
  }
  if (offdiag) {  // column block receives row-sums of the transposed tile
#pragma unroll
    for (int n = 0; n < 4; ++n) {
      float c = cs[n];
      c += __shfl_xor(c, 16, 64);
      c += __shfl_xor(c, 32, 64);
      if ((lane >> 4) == 0)
        rowPartial[(size_t)(bi * 2 + wr) * N + (bcol + wc * 64 + n * 16 + lane)] = c;
    }
  }
}

// ---------------- Kernel 3: row logsumexp-target + deterministic final mean --
__global__ __launch_bounds__(256) void k_rowreduce(const float* __restrict__ rowPartial,
                                                   const float* __restrict__ simTgt,
                                                   float* __restrict__ blockOut,
                                                   unsigned* __restrict__ ticket,
                                                   float* __restrict__ out, int N) {
  const int row = blockIdx.x * 256 + threadIdx.x;
  float denom = 0.f;
#pragma unroll 8
  for (int c = 0; c < 128; ++c) denom += rowPartial[(size_t)c * N + row];
  // v_log_f32 = log2; loss = (log2(denom) - sv2) * ln2
  float lossr = (__builtin_amdgcn_logf(denom) - simTgt[row]) * LN2;
#pragma unroll
  for (int d = 32; d; d >>= 1) lossr += __shfl_xor(lossr, d, 64);
  __shared__ float red[4];
  __shared__ int isLast;
  if ((threadIdx.x & 63) == 0) red[threadIdx.x >> 6] = lossr;
  __syncthreads();
  if (threadIdx.x == 0) {
    // device-scope RMW write: coherent across XCDs, deterministic value
    atomicExch(&blockOut[blockIdx.x], red[0] + red[1] + red[2] + red[3]);
    isLast = (atomicAdd(ticket, 1u) == gridDim.x - 1);
  }
  __syncthreads();
  if (isLast && threadIdx.x < 64) {
    // coherent read of every block sum via atomic RMW (+0.0f), fixed order
    float v = (threadIdx.x < gridDim.x) ? atomicAdd(&blockOut[threadIdx.x], 0.0f) : 0.f;
#pragma unroll
    for (int d = 32; d; d >>= 1) v += __shfl_xor(v, d, 64);
    if (threadIdx.x == 0) out[0] = v / (float)N;
  }
}

extern "C" void kernel_launch(void* const* d_in, const int* in_sizes, int n_in,
                              void* d_out, int out_size, void* d_ws, size_t ws_size,
                              hipStream_t stream) {
  const float* ei = (const float*)d_in[0];
  const float* ej = (const float*)d_in[1];
  const int B = in_sizes[0] / D_DIM;  // 4096
  const int N = 2 * B;                // 8192

  char* ws = (char*)d_ws;
  unsigned short* R = (unsigned short*)ws;                                   // N*256*2 = 4MB
  float* rowPartial = (float*)(ws + (size_t)N * D_DIM * 2);                  // 128*N*4 = 4MB
  float* simTgt     = (float*)(ws + (size_t)N * D_DIM * 2 + (size_t)128 * N * 4);  // N*4
  float* blockOut   = (float*)((char*)simTgt + (size_t)N * 4);               // (N/256)*4
  unsigned* ticket  = (unsigned*)((char*)blockOut + (size_t)(N / 256) * 4);  // 4B

  k_normalize<<<N / 4, 256, 0, stream>>>(ei, ej, R, ticket, B);
  const int T = N / 128;
  k_simgemm<<<T * (T + 1) / 2, 256, 0, stream>>>(R, rowPartial, simTgt, N);
  k_rowreduce<<<N / 256, 256, 0, stream>>>(rowPartial, simTgt, blockOut, ticket,
                                           (float*)d_out, N);
}

// Round 7
// 49.406 us; speedup vs baseline: 1.9268x; 1.9268x over previous
//
#include <hip/hip_runtime.h>

typedef __bf16 bf16x8 __attribute__((ext_vector_type(8)));
typedef float f32x4 __attribute__((ext_vector_type(4)));

#define D_DIM 256
// base-2 scale: sv2 = acc * INV_T * log2(e); exp(sv)=2^(sv2)
#define C2 2.88539008f
#define LN2 0.69314718f

__device__ __forceinline__ unsigned short f2bf(float f) {
  union { float f; unsigned u; } x; x.f = f;
  unsigned r = x.u + 0x7FFFu + ((x.u >> 16) & 1u);  // round-to-nearest-even
  return (unsigned short)(r >> 16);
}

// ---------------- Kernel 1: L2-normalize [emb_i; emb_j] -> bf16 R[N][256] ----
__global__ __launch_bounds__(256) void k_normalize(const float* __restrict__ ei,
                                                   const float* __restrict__ ej,
                                                   unsigned short* __restrict__ R,
                                                   unsigned* __restrict__ ticket,
                                                   int B) {
  if (blockIdx.x == 0 && threadIdx.x == 0) *ticket = 0u;  // per-call reset
  const int w = threadIdx.x >> 6, lane = threadIdx.x & 63;
  const int row = blockIdx.x * 4 + w;
  const float* src = (row < B) ? (ei + (size_t)row * D_DIM)
                               : (ej + (size_t)(row - B) * D_DIM);
  float4 v = reinterpret_cast<const float4*>(src)[lane];  // 64 lanes * 4 = 256
  float ss = v.x * v.x + v.y * v.y + v.z * v.z + v.w * v.w;
#pragma unroll
  for (int d = 32; d; d >>= 1) ss += __shfl_xor(ss, d, 64);
  float s = 1.0f / fmaxf(sqrtf(ss), 1e-12f);
  ushort4 o;
  o.x = f2bf(v.x * s); o.y = f2bf(v.y * s);
  o.z = f2bf(v.z * s); o.w = f2bf(v.w * s);
  reinterpret_cast<ushort4*>(R + (size_t)row * D_DIM)[lane] = o;
}

// ---------------- Kernel 2: symmetric fused sim GEMM + exp partials ---------
// Upper-triangular 128x128 tiles (bi <= bj); off-diag tiles feed both row and
// column blocks (sim symmetric). BK=32 TRIPLE-buffered LDS (48KB, 3 blocks/CU)
// with depth-2 prefetch: vmcnt(8) keeps 2 K-steps of loads in flight across
// barriers, covering the ~250cy L2 latency (R5's depth-1 covered only ~150cy).
__global__ __launch_bounds__(256, 3) void k_simgemm(const unsigned short* __restrict__ R,
                                                    float* __restrict__ rowPartial,
                                                    float* __restrict__ simTgt,
                                                    int N) {
  __shared__ char lds[3][16 * 1024];  // per buf: A panel 8KB + B panel 8KB
  const int tid = threadIdx.x;
  const int w = tid >> 6, lane = tid & 63;
  const int wr = w >> 1, wc = w & 1;
  const int half = N >> 1;

  // decode linear block id -> upper-triangular (bi, bj), bi <= bj
  const int T = N / 128;  // 64
  const int t = blockIdx.x;
  int bi = (int)(((float)(2 * T + 1) -
                  sqrtf((float)((2 * T + 1) * (2 * T + 1) - 8 * t))) * 0.5f);
  while (bi > 0 && t < bi * (2 * T - bi + 1) / 2) --bi;
  while (t >= (bi + 1) * (2 * T - bi) / 2) ++bi;
  const int bj = bi + (t - bi * (2 * T - bi + 1) / 2);
  const int brow = bi * 128, bcol = bj * 128;
  const bool offdiag = (bi != bj);

  f32x4 zero4 = {0.f, 0.f, 0.f, 0.f};
  f32x4 acc[4][4];
#pragma unroll
  for (int m = 0; m < 4; ++m)
#pragma unroll
    for (int n = 0; n < 4; ++n) acc[m][n] = zero4;

  // Stage one BK=32 K-slice (A panel rows, B panel cols) into lds[buf].
  // Row = 64B = 4 chunks of 16B. Swizzle: position js holds global chunk
  // j = js ^ ((r>>1)&3)  (involution; reader applies same XOR).
  auto stage = [&](int buf, int kt) {
    char* dst = lds[buf];
#pragma unroll
    for (int i = 0; i < 4; ++i) {
      const int grp = i * 4 + w;              // 16 grps x 64 chunks of 16B
      const int cp = (grp & 7) * 64 + lane;   // chunk within panel, 0..511
      const int r = cp >> 2, js = cp & 3;
      const int j = js ^ ((r >> 1) & 3);      // inverse swizzle on source
      const int base = (grp < 8) ? brow : bcol;
      const unsigned short* g = R + (size_t)(base + r) * D_DIM + kt * 32 + j * 8;
      __builtin_amdgcn_global_load_lds(
          (const __attribute__((address_space(1))) void*)g,
          (__attribute__((address_space(3))) void*)(dst + (size_t)grp * 1024), 16, 0, 0);
    }
  };

  auto compute = [&](int buf) {
    const char* ldsA = lds[buf];
    const char* ldsB = lds[buf] + 8 * 1024;
    const int k8 = lane >> 4;  // k-chunk 0..3 (8 bf16 each)
    bf16x8 a[4], b[4];
#pragma unroll
    for (int m = 0; m < 4; ++m) {
      const int row = wr * 64 + m * 16 + (lane & 15);
      a[m] = *reinterpret_cast<const bf16x8*>(ldsA + (row * 4 + (k8 ^ ((row >> 1) & 3))) * 16);
    }
#pragma unroll
    for (int n = 0; n < 4; ++n) {
      const int col = wc * 64 + n * 16 + (lane & 15);
      b[n] = *reinterpret_cast<const bf16x8*>(ldsB + (col * 4 + (k8 ^ ((col >> 1) & 3))) * 16);
    }
#pragma unroll
    for (int m = 0; m < 4; ++m)
#pragma unroll
      for (int n = 0; n < 4; ++n)
        acc[m][n] = __builtin_amdgcn_mfma_f32_16x16x32_bf16(a[m], b[n], acc[m][n], 0, 0, 0);
  };

  stage(0, 0);  // prologue: depth-2 -> 8 loads/wave in flight
  stage(1, 1);
#pragma unroll
  for (int kt = 0; kt < 8; ++kt) {  // K = 256 = 8 * 32
    if (kt < 6) {
      stage((kt + 2) % 3, kt + 2);  // outstanding: 12
      asm volatile("s_waitcnt vmcnt(8)" ::: "memory");   // kt's buf landed
    } else if (kt == 6) {
      asm volatile("s_waitcnt vmcnt(4)" ::: "memory");   // kt6 landed, kt7 in flight
    } else {
      asm volatile("s_waitcnt vmcnt(0)" ::: "memory");
    }
    __builtin_amdgcn_s_barrier();   // all waves' kt-buf writes visible
    compute(kt % 3);
    __builtin_amdgcn_s_barrier();   // all reads of kt-buf done before overwrite
  }

  // epilogue (base-2): scale, mask diag, capture targets, exp2, row-direction
  // sums (over tile cols) + column-direction sums (over rows, symmetry)
  float cs[4] = {0.f, 0.f, 0.f, 0.f};
#pragma unroll
  for (int m = 0; m < 4; ++m) {
#pragma unroll
    for (int j = 0; j < 4; ++j) {
      const int gr = brow + wr * 64 + m * 16 + (lane >> 4) * 4 + j;
      const int tgt = (gr < half) ? gr + half : gr - half;
      float rs = 0.f;
#pragma unroll
      for (int n = 0; n < 4; ++n) {
        const int gc = bcol + wc * 64 + n * 16 + (lane & 15);
        const float sv2 = acc[m][n][j] * C2;
        const float ev = (gr == gc) ? 0.f : __builtin_amdgcn_exp2f(sv2);
        if (gc == tgt) {                  // involution: also gr == tgt(gc)
          simTgt[gr] = sv2;
          if (offdiag) simTgt[gc] = sv2;  // sim symmetric
        }
        rs += ev;
        cs[n] += ev;
      }
#pragma unroll
      for (int d = 1; d < 16; d <<= 1) rs += __shfl_xor(rs, d, 64);
      if ((lane & 15) == 0)
        rowPartial[(size_t)(bj * 2 + wc) * N + gr] = rs;
    }
  }
  if (offdiag) {  // column block receives row-sums of the transposed tile
#pragma unroll
    for (int n = 0; n < 4; ++n) {
      float c = cs[n];
      c += __shfl_xor(c, 16, 64);
      c += __shfl_xor(c, 32, 64);
      if ((lane >> 4) == 0)
        rowPartial[(size_t)(bi * 2 + wr) * N + (bcol + wc * 64 + n * 16 + lane)] = c;
    }
  }
}

// ---------------- Kernel 3: row logsumexp-target + deterministic final mean --
// 128 blocks x 64 rows; each wave sums a 32-slice of the 128 partials,
// LDS-combine, wave 0 finishes the row and block sum. Last block (ticket)
// reduces the 128 block sums.
__global__ __launch_bounds__(256) void k_rowreduce(const float* __restrict__ rowPartial,
                                                   const float* __restrict__ simTgt,
                                                   float* __restrict__ blockOut,
                                                   unsigned* __restrict__ ticket,
                                                   float* __restrict__ out, int N) {
  const int lane = threadIdx.x & 63;   // row within this block's 64
  const int q = threadIdx.x >> 6;      // partial-chunk 0..3
  const int row = blockIdx.x * 64 + lane;
  float part = 0.f;
#pragma unroll 8
  for (int c = q * 32; c < q * 32 + 32; ++c)
    part += rowPartial[(size_t)c * N + row];
  __shared__ float red[4][64];
  __shared__ int isLast;
  red[q][lane] = part;
  __syncthreads();
  if (threadIdx.x < 64) {
    const float denom = red[0][lane] + red[1][lane] + red[2][lane] + red[3][lane];
    // v_log_f32 = log2; loss = (log2(denom) - sv2) * ln2
    float lossr = (__builtin_amdgcn_logf(denom) - simTgt[row]) * LN2;
#pragma unroll
    for (int d = 32; d; d >>= 1) lossr += __shfl_xor(lossr, d, 64);
    if (threadIdx.x == 0) {
      // device-scope RMW write: coherent across XCDs, deterministic value
      atomicExch(&blockOut[blockIdx.x], lossr);
      isLast = (atomicAdd(ticket, 1u) == gridDim.x - 1);
    }
  }
  __syncthreads();
  if (isLast && threadIdx.x < 64) {
    // coherent read of all 128 block sums via atomic RMW (+0.0f), fixed order
    float v = atomicAdd(&blockOut[threadIdx.x], 0.0f) +
              atomicAdd(&blockOut[64 + threadIdx.x], 0.0f);
#pragma unroll
    for (int d = 32; d; d >>= 1) v += __shfl_xor(v, d, 64);
    if (threadIdx.x == 0) out[0] = v / (float)N;
  }
}

extern "C" void kernel_launch(void* const* d_in, const int* in_sizes, int n_in,
                              void* d_out, int out_size, void* d_ws, size_t ws_size,
                              hipStream_t stream) {
  const float* ei = (const float*)d_in[0];
  const float* ej = (const float*)d_in[1];
  const int B = in_sizes[0] / D_DIM;  // 4096
  const int N = 2 * B;                // 8192

  char* ws = (char*)d_ws;
  unsigned short* R = (unsigned short*)ws;                                   // N*256*2 = 4MB
  float* rowPartial = (float*)(ws + (size_t)N * D_DIM * 2);                  // 128*N*4 = 4MB
  float* simTgt     = (float*)(ws + (size_t)N * D_DIM * 2 + (size_t)128 * N * 4);  // N*4
  float* blockOut   = (float*)((char*)simTgt + (size_t)N * 4);               // 128*4
  unsigned* ticket  = (unsigned*)((char*)blockOut + 128 * 4);                // 4B

  k_normalize<<<N / 4, 256, 0, stream>>>(ei, ej, R, ticket, B);
  const int T = N / 128;
  k_simgemm<<<T * (T + 1) / 2, 256, 0, stream>>>(R, rowPartial, simTgt, N);
  k_rowreduce<<<N / 64, 256, 0, stream>>>(rowPartial, simTgt, blockOut, ticket,
                                          (float*)d_out, N);
}